// Round 1
// baseline (1595.285 us; speedup 1.0000x reference)
//
#include <hip/hip_runtime.h>
#include <hip/hip_bf16.h>

#define N_ROWS 100000
#define T_DIM  512
#define DIN    256
#define DH     256

typedef _Float16 h2 __attribute__((ext_vector_type(2)));
typedef _Float16 h8 __attribute__((ext_vector_type(8)));

#if __has_builtin(__builtin_amdgcn_fdot2)
static __device__ __forceinline__ float dot2f(h2 a, h2 b, float c) {
  return __builtin_amdgcn_fdot2(a, b, c, false);
}
#else
static __device__ __forceinline__ float dot2f(h2 a, h2 b, float c) {
  return c + (float)a[0] * (float)b[0] + (float)a[1] * (float)b[1];
}
#endif

// ---------------- Kernel 1: ve[t][:] = sum_{n: H[n,t]!=0} X[n,:] ----------------
__global__ __launch_bounds__(256) void k_aggregate(
    const float* __restrict__ X, const float* __restrict__ H,
    float* __restrict__ ve)
{
  __shared__ int cnt;
  __shared__ short list[T_DIM];
  const int tid = threadIdx.x;
  for (int n = blockIdx.x; n < N_ROWS; n += gridDim.x) {
    if (tid == 0) cnt = 0;
    __syncthreads();
    // H row: thread tid covers t = 2*tid, 2*tid+1 (coalesced float2)
    const float2 hp = *(const float2*)(&H[(size_t)n * T_DIM + 2 * tid]);
    if (hp.x != 0.0f) { int idx = atomicAdd(&cnt, 1); list[idx] = (short)(2 * tid); }
    if (hp.y != 0.0f) { int idx = atomicAdd(&cnt, 1); list[idx] = (short)(2 * tid + 1); }
    __syncthreads();
    const int c = cnt;
    if (c > 0) {
      const float xv = X[(size_t)n * DIN + tid];
      for (int i = 0; i < c; ++i) {
        const int t = list[i];
        atomicAdd(&ve[t * DIN + tid], xv);
      }
    }
    __syncthreads();
  }
}

// ---------------- Kernel 2: gx[t][j] = b_ih[j] + sum_k ve[t][k]*W_ih[j][k] ------
__global__ __launch_bounds__(256) void k_gx(
    const float* __restrict__ ve, const float* __restrict__ Wih,
    const float* __restrict__ bih, float* __restrict__ gx)
{
  __shared__ float vl[DIN];
  const int t = blockIdx.x, j = threadIdx.x;
  vl[j] = ve[t * DIN + j];
  __syncthreads();
  float a0 = bih[j], a1 = bih[256 + j], a2 = bih[512 + j];
  const float* __restrict__ w0 = &Wih[(size_t)j * DIN];
  const float* __restrict__ w1 = &Wih[(size_t)(j + 256) * DIN];
  const float* __restrict__ w2 = &Wih[(size_t)(j + 512) * DIN];
#pragma unroll 4
  for (int k = 0; k < DIN; ++k) {
    const float v = vl[k];
    a0 = fmaf(w0[k], v, a0);
    a1 = fmaf(w1[k], v, a1);
    a2 = fmaf(w2[k], v, a2);
  }
  gx[t * 768 + j]       = a0;
  gx[t * 768 + 256 + j] = a1;
  gx[t * 768 + 512 + j] = a2;
}

// ---------------- Kernel 3: GRU scan (single block, W_hh in VGPRs as f16) + attention
__global__ __launch_bounds__(768) void k_gru_att(
    const float* __restrict__ Whh, const float* __restrict__ bhh,
    const float* __restrict__ gx, const float* __restrict__ watt,
    float* __restrict__ hs, float* __restrict__ out)
{
  __shared__ h8 hbuf8[DH / 8];   // packed f16 h_{t-1}
  __shared__ float gh[768];      // gate pre-activations / reused as score buffer
  __shared__ float red[2];
  const int j = threadIdx.x;

  // Thread j owns W_hh row j in registers as 128 packed f16 pairs.
  h2 w[128];
  {
    const float2* __restrict__ row = (const float2*)&Whh[(size_t)j * DH];
#pragma unroll
    for (int c = 0; c < 128; ++c) {
      const float2 p = row[c];
      h2 v; v[0] = (_Float16)p.x; v[1] = (_Float16)p.y;
      w[c] = v;
    }
  }
  float bhr = 0.f, bhz = 0.f, bhn = 0.f, h = 0.f;
  if (j < 256) { bhr = bhh[j]; bhz = bhh[256 + j]; bhn = bhh[512 + j]; }
  _Float16* hb = (_Float16*)hbuf8;
  if (j < 256) hb[j] = (_Float16)0.f;
  __syncthreads();

  for (int t = 0; t < T_DIM; ++t) {
    // issue gx loads early so L2 latency hides under the dot phase
    float gxr = 0.f, gxz = 0.f, gxn = 0.f;
    if (j < 256) {
      gxr = gx[t * 768 + j];
      gxz = gx[t * 768 + 256 + j];
      gxn = gx[t * 768 + 512 + j];
    }
    // gh[j] = W_hh[j,:] . h  (f16 inputs, f32 accumulate)
    float acc = 0.f;
#pragma unroll
    for (int c = 0; c < 32; ++c) {
      const h8 hv = hbuf8[c];                       // ds_read_b128, broadcast
      const h2 p0 = __builtin_shufflevector(hv, hv, 0, 1);
      const h2 p1 = __builtin_shufflevector(hv, hv, 2, 3);
      const h2 p2 = __builtin_shufflevector(hv, hv, 4, 5);
      const h2 p3 = __builtin_shufflevector(hv, hv, 6, 7);
      acc = dot2f(w[4 * c + 0], p0, acc);
      acc = dot2f(w[4 * c + 1], p1, acc);
      acc = dot2f(w[4 * c + 2], p2, acc);
      acc = dot2f(w[4 * c + 3], p3, acc);
    }
    gh[j] = acc;
    __syncthreads();
    if (j < 256) {
      const float pr = gxr + gh[j] + bhr;
      const float pz = gxz + gh[256 + j] + bhz;
      const float gn = gh[512 + j] + bhn;
      const float r = 1.f / (1.f + __expf(-pr));
      const float z = 1.f / (1.f + __expf(-pz));
      const float pn = gxn + r * gn;
      const float n = 2.f / (1.f + __expf(-2.f * pn)) - 1.f;   // tanh
      h = (1.f - z) * n + z * h;
      hs[t * DH + j] = h;
      hb[j] = (_Float16)h;
    }
    __syncthreads();
  }

  // ---- attention epilogue: alpha = softmax(hs @ w_att); out = alpha^T hs ----
  if (j < T_DIM) {
    const float* __restrict__ hr = &hs[j * DH];
    float s = 0.f;
#pragma unroll 4
    for (int k = 0; k < DH; ++k) s = fmaf(hr[k], watt[k], s);
    gh[j] = s;
  }
  __syncthreads();
  if (j < 64) {
    float m = -1e30f;
#pragma unroll
    for (int i = 0; i < 8; ++i) m = fmaxf(m, gh[j * 8 + i]);
#pragma unroll
    for (int off = 32; off > 0; off >>= 1) m = fmaxf(m, __shfl_down(m, off));
    if (j == 0) red[0] = m;
  }
  __syncthreads();
  const float M = red[0];
  if (j < T_DIM) gh[j] = __expf(gh[j] - M);
  __syncthreads();
  if (j < 64) {
    float s = 0.f;
#pragma unroll
    for (int i = 0; i < 8; ++i) s += gh[j * 8 + i];
#pragma unroll
    for (int off = 32; off > 0; off >>= 1) s += __shfl_down(s, off);
    if (j == 0) red[1] = s;
  }
  __syncthreads();
  const float inv = 1.f / red[1];
  if (j < 256) {
    float acc = 0.f;
    for (int t = 0; t < T_DIM; ++t) acc = fmaf(gh[t], hs[t * DH + j], acc);
    out[j] = acc * inv;
  }
}

extern "C" void kernel_launch(void* const* d_in, const int* in_sizes, int n_in,
                              void* d_out, int out_size, void* d_ws, size_t ws_size,
                              hipStream_t stream) {
  const float* X    = (const float*)d_in[0];
  const float* H    = (const float*)d_in[1];
  const float* Wih  = (const float*)d_in[2];
  const float* Whh  = (const float*)d_in[3];
  const float* bih  = (const float*)d_in[4];
  const float* bhh  = (const float*)d_in[5];
  const float* watt = (const float*)d_in[6];
  float* out = (float*)d_out;

  char* ws = (char*)d_ws;
  float* ve = (float*)ws;                                   // 512*256 f32
  float* gx = (float*)(ws + T_DIM * DIN * 4);               // 512*768 f32
  float* hs = (float*)(ws + T_DIM * DIN * 4 + T_DIM * 768 * 4); // 512*256 f32

  hipMemsetAsync(ve, 0, T_DIM * DIN * sizeof(float), stream);
  k_aggregate<<<2048, 256, 0, stream>>>(X, H, ve);
  k_gx<<<T_DIM, 256, 0, stream>>>(ve, Wih, bih, gx);
  k_gru_att<<<1, 768, 0, stream>>>(Whh, bhh, gx, watt, hs, out);
}

// Round 2
// 972.078 us; speedup vs baseline: 1.6411x; 1.6411x over previous
//
#include <hip/hip_runtime.h>
#include <hip/hip_bf16.h>

#define N_ROWS 100000
#define T_DIM  512
#define DIN    256
#define DH     256
#define KC     800
#define NSTEP  25      // KC / 32
#define NCHUNK 125     // 125 * 800 = 100000 exactly

typedef __attribute__((ext_vector_type(8))) short s16x8;
typedef __attribute__((ext_vector_type(4))) float f32x4;
typedef _Float16 h2 __attribute__((ext_vector_type(2)));
typedef _Float16 h8 __attribute__((ext_vector_type(8)));

#if __has_builtin(__builtin_amdgcn_fdot2)
static __device__ __forceinline__ float dot2f(h2 a, h2 b, float c) {
  return __builtin_amdgcn_fdot2(a, b, c, false);
}
#else
static __device__ __forceinline__ float dot2f(h2 a, h2 b, float c) {
  return c + (float)a[0] * (float)b[0] + (float)a[1] * (float)b[1];
}
#endif

// pack two f32 into bf16 pair (RTNE), low = lo, high = hi
static __device__ __forceinline__ unsigned bf16pair(float lo, float hi) {
  unsigned a = __builtin_bit_cast(unsigned, lo);
  unsigned b = __builtin_bit_cast(unsigned, hi);
  a = (a + 0x7fffu + ((a >> 16) & 1u)) >> 16;
  b = (b + 0x7fffu + ((b >> 16) & 1u)) & 0xffff0000u;
  return a | b;
}

// ---------------- Kernel 1: ve = H^T @ X as dense bf16 MFMA GEMM, split-K ----
// A = H^T : A[m=t][k=n]  (H stored [k][m], K-major)
// B = X   : B[k][n=d]    (K-major)
// grid = 2 M-tiles x 125 K-chunks; each block: 256x256 output tile, K-chunk 800.
__global__ __launch_bounds__(512, 2) void k_agg_mfma(
    const float* __restrict__ X, const float* __restrict__ Hm,
    float* __restrict__ ve, float* __restrict__ ve_part, int use_part)
{
  __shared__ unsigned smem[8192];   // A: [0,4096) u32, B: [4096,8192) ; 32 KB
  const int tid  = threadIdx.x;
  const int mt   = blockIdx.x & 1;
  const int kc   = blockIdx.x >> 1;
  const int m0   = mt * 256;
  const int k0   = kc * KC;
  const int lane = tid & 63;
  const int wv   = tid >> 6;        // 8 waves: 2 (wm) x 4 (wn)
  const int wm   = wv >> 2, wn = wv & 3;

  f32x4 acc[8][4] = {};

  // staging: unit u in [0,1024): kp = u>>6 (k-pair 0..15), g = u&63 (float4 col group)
  // thread covers units tid and tid+512  ->  kp0 = tid>>6 (0..7), kp1 = kp0+8, same g
  const int kp0 = tid >> 6;
  const int kp1 = kp0 + 8;
  const int gg  = tid & 63;

  float4 ra0, ra1, ra2, ra3, rb0, rb1, rb2, rb3;

  auto load_tile = [&](int kt) {
    const size_t kb = (size_t)(k0 + kt * 32);
    const float* pa0 = &Hm[(kb + 2 * kp0) * T_DIM + m0 + gg * 4];
    ra0 = *(const float4*)pa0;
    ra1 = *(const float4*)(pa0 + T_DIM);
    const float* pa1 = &Hm[(kb + 2 * kp1) * T_DIM + m0 + gg * 4];
    ra2 = *(const float4*)pa1;
    ra3 = *(const float4*)(pa1 + T_DIM);
    const float* pb0 = &X[(kb + 2 * kp0) * DIN + gg * 4];
    rb0 = *(const float4*)pb0;
    rb1 = *(const float4*)(pb0 + DIN);
    const float* pb1 = &X[(kb + 2 * kp1) * DIN + gg * 4];
    rb2 = *(const float4*)pb1;
    rb3 = *(const float4*)(pb1 + DIN);
  };

  // LDS layout: row m (256 rows, 64B = 16 u32 of k-pairs), kp-block XOR swizzle:
  // u32 index = m*16 + (kp ^ ((m&3)<<2))
  auto store_tile = [&]() {
#pragma unroll
    for (int d = 0; d < 4; ++d) {
      const int m  = gg * 4 + d;
      const int sw = d << 2;                 // (m&3)<<2 == d<<2
      smem[m * 16 + (kp0 ^ sw)]        = bf16pair(((const float*)&ra0)[d], ((const float*)&ra1)[d]);
      smem[m * 16 + (kp1 ^ sw)]        = bf16pair(((const float*)&ra2)[d], ((const float*)&ra3)[d]);
      smem[4096 + m * 16 + (kp0 ^ sw)] = bf16pair(((const float*)&rb0)[d], ((const float*)&rb1)[d]);
      smem[4096 + m * 16 + (kp1 ^ sw)] = bf16pair(((const float*)&rb2)[d], ((const float*)&rb3)[d]);
    }
  };

  auto compute = [&]() {
    const uint4* sv = (const uint4*)smem;
    s16x8 af[8], bfr[4];
#pragma unroll
    for (int fm = 0; fm < 8; ++fm) {
      const int m = wm * 128 + fm * 16 + (lane & 15);
      af[fm] = __builtin_bit_cast(s16x8, sv[m * 4 + ((lane >> 4) ^ (m & 3))]);
    }
#pragma unroll
    for (int fn = 0; fn < 4; ++fn) {
      const int n = wn * 64 + fn * 16 + (lane & 15);
      bfr[fn] = __builtin_bit_cast(s16x8, sv[1024 + n * 4 + ((lane >> 4) ^ (n & 3))]);
    }
#pragma unroll
    for (int fm = 0; fm < 8; ++fm)
#pragma unroll
      for (int fn = 0; fn < 4; ++fn)
        acc[fm][fn] = __builtin_amdgcn_mfma_f32_16x16x32_bf16(af[fm], bfr[fn], acc[fm][fn], 0, 0, 0);
  };

  load_tile(0);
  store_tile();
  for (int kt = 0; kt < NSTEP; ++kt) {
    __syncthreads();                      // tile kt visible in LDS
    if (kt + 1 < NSTEP) load_tile(kt + 1);   // issue next global loads early
    compute();
    __syncthreads();                      // all waves done reading tile kt
    if (kt + 1 < NSTEP) store_tile();
  }

  // epilogue: C/D layout col = lane&15, row = (lane>>4)*4 + reg  [verified m89/m91]
  if (use_part) {
    float* dst = ve_part + (size_t)kc * (512 * 256);
#pragma unroll
    for (int fm = 0; fm < 8; ++fm) {
      const int r0 = m0 + wm * 128 + fm * 16 + (lane >> 4) * 4;
#pragma unroll
      for (int fn = 0; fn < 4; ++fn) {
        const int cc = wn * 64 + fn * 16 + (lane & 15);
#pragma unroll
        for (int q = 0; q < 4; ++q)
          dst[(size_t)(r0 + q) * 256 + cc] = acc[fm][fn][q];
      }
    }
  } else {
#pragma unroll
    for (int fm = 0; fm < 8; ++fm) {
      const int r0 = m0 + wm * 128 + fm * 16 + (lane >> 4) * 4;
#pragma unroll
      for (int fn = 0; fn < 4; ++fn) {
        const int cc = wn * 64 + fn * 16 + (lane & 15);
#pragma unroll
        for (int q = 0; q < 4; ++q)
          atomicAdd(&ve[(size_t)(r0 + q) * 256 + cc], acc[fm][fn][q]);
      }
    }
  }
}

// ---------------- Kernel 2: reduce split-K partials + gx = ve @ W_ih^T + b ----
__global__ __launch_bounds__(256) void k_gx(
    const float* __restrict__ vesrc, int npart,
    const float* __restrict__ Wih, const float* __restrict__ bih,
    float* __restrict__ gx)
{
  __shared__ float vl[DIN];
  const int t = blockIdx.x, j = threadIdx.x;
  float s = 0.f;
  for (int p = 0; p < npart; ++p) s += vesrc[(size_t)p * (512 * 256) + t * DIN + j];
  vl[j] = s;
  __syncthreads();
  float a0 = bih[j], a1 = bih[256 + j], a2 = bih[512 + j];
  const float* __restrict__ w0 = &Wih[(size_t)j * DIN];
  const float* __restrict__ w1 = &Wih[(size_t)(j + 256) * DIN];
  const float* __restrict__ w2 = &Wih[(size_t)(j + 512) * DIN];
#pragma unroll 4
  for (int k = 0; k < DIN; ++k) {
    const float v = vl[k];
    a0 = fmaf(w0[k], v, a0);
    a1 = fmaf(w1[k], v, a1);
    a2 = fmaf(w2[k], v, a2);
  }
  gx[t * 768 + j]       = a0;
  gx[t * 768 + 256 + j] = a1;
  gx[t * 768 + 512 + j] = a2;
}

// ---------------- Kernel 3: GRU scan (single block, W_hh in VGPRs as f16) + attention
__global__ __launch_bounds__(768) void k_gru_att(
    const float* __restrict__ Whh, const float* __restrict__ bhh,
    const float* __restrict__ gx, const float* __restrict__ watt,
    float* __restrict__ hs, float* __restrict__ out)
{
  __shared__ h8 hbuf8[DH / 8];   // packed f16 h_{t-1}
  __shared__ float gh[768];
  __shared__ float red[2];
  const int j = threadIdx.x;

  h2 w[128];
  {
    const float2* __restrict__ row = (const float2*)&Whh[(size_t)j * DH];
#pragma unroll
    for (int c = 0; c < 128; ++c) {
      const float2 p = row[c];
      h2 v; v[0] = (_Float16)p.x; v[1] = (_Float16)p.y;
      w[c] = v;
    }
  }
  float bhr = 0.f, bhz = 0.f, bhn = 0.f, h = 0.f;
  if (j < 256) { bhr = bhh[j]; bhz = bhh[256 + j]; bhn = bhh[512 + j]; }
  _Float16* hb = (_Float16*)hbuf8;
  if (j < 256) hb[j] = (_Float16)0.f;
  __syncthreads();

  for (int t = 0; t < T_DIM; ++t) {
    float gxr = 0.f, gxz = 0.f, gxn = 0.f;
    if (j < 256) {
      gxr = gx[t * 768 + j];
      gxz = gx[t * 768 + 256 + j];
      gxn = gx[t * 768 + 512 + j];
    }
    // gh[j] = W_hh[j,:] . h   -- 4 independent accumulator chains for ILP
    float a0 = 0.f, a1 = 0.f, a2 = 0.f, a3 = 0.f;
#pragma unroll
    for (int c = 0; c < 32; ++c) {
      const h8 hv = hbuf8[c];
      const h2 p0 = __builtin_shufflevector(hv, hv, 0, 1);
      const h2 p1 = __builtin_shufflevector(hv, hv, 2, 3);
      const h2 p2 = __builtin_shufflevector(hv, hv, 4, 5);
      const h2 p3 = __builtin_shufflevector(hv, hv, 6, 7);
      a0 = dot2f(w[4 * c + 0], p0, a0);
      a1 = dot2f(w[4 * c + 1], p1, a1);
      a2 = dot2f(w[4 * c + 2], p2, a2);
      a3 = dot2f(w[4 * c + 3], p3, a3);
    }
    gh[j] = (a0 + a1) + (a2 + a3);
    __syncthreads();
    if (j < 256) {
      const float pr = gxr + gh[j] + bhr;
      const float pz = gxz + gh[256 + j] + bhz;
      const float gn = gh[512 + j] + bhn;
      const float r = 1.f / (1.f + __expf(-pr));
      const float z = 1.f / (1.f + __expf(-pz));
      const float pn = gxn + r * gn;
      const float n = 2.f / (1.f + __expf(-2.f * pn)) - 1.f;   // tanh
      h = (1.f - z) * n + z * h;
      hs[t * DH + j] = h;
      hb[j] = (_Float16)h;
    }
    __syncthreads();
  }

  // ---- attention epilogue ----
  if (j < T_DIM) {
    const float* __restrict__ hr = &hs[j * DH];
    float s = 0.f;
#pragma unroll 4
    for (int k = 0; k < DH; ++k) s = fmaf(hr[k], watt[k], s);
    gh[j] = s;
  }
  __syncthreads();
  if (j < 64) {
    float m = -1e30f;
#pragma unroll
    for (int i = 0; i < 8; ++i) m = fmaxf(m, gh[j * 8 + i]);
#pragma unroll
    for (int off = 32; off > 0; off >>= 1) m = fmaxf(m, __shfl_down(m, off));
    if (j == 0) red[0] = m;
  }
  __syncthreads();
  const float M = red[0];
  if (j < T_DIM) gh[j] = __expf(gh[j] - M);
  __syncthreads();
  if (j < 64) {
    float s = 0.f;
#pragma unroll
    for (int i = 0; i < 8; ++i) s += gh[j * 8 + i];
#pragma unroll
    for (int off = 32; off > 0; off >>= 1) s += __shfl_down(s, off);
    if (j == 0) red[1] = s;
  }
  __syncthreads();
  const float inv = 1.f / red[1];
  if (j < 256) {
    float acc = 0.f;
    for (int t = 0; t < T_DIM; ++t) acc = fmaf(gh[t], hs[t * DH + j], acc);
    out[j] = acc * inv;
  }
}

extern "C" void kernel_launch(void* const* d_in, const int* in_sizes, int n_in,
                              void* d_out, int out_size, void* d_ws, size_t ws_size,
                              hipStream_t stream) {
  const float* X    = (const float*)d_in[0];
  const float* H    = (const float*)d_in[1];
  const float* Wih  = (const float*)d_in[2];
  const float* Whh  = (const float*)d_in[3];
  const float* bih  = (const float*)d_in[4];
  const float* bhh  = (const float*)d_in[5];
  const float* watt = (const float*)d_in[6];
  float* out = (float*)d_out;

  char* ws = (char*)d_ws;
  float* gx      = (float*)ws;                        // 512*768*4 = 1572864 B
  float* hs      = (float*)(ws + 1572864);            // 512*256*4 = 524288 B
  float* ve      = (float*)(ws + 2097152);            // 524288 B (atomic fallback)
  float* ve_part = (float*)(ws + 2621440);            // 125*512*256*4 = 65536000 B

  const size_t need_part = 2621440 + 65536000;
  const int use_part = (ws_size >= need_part) ? 1 : 0;

  if (!use_part)
    hipMemsetAsync(ve, 0, T_DIM * DIN * sizeof(float), stream);

  k_agg_mfma<<<2 * NCHUNK, 512, 0, stream>>>(X, H, ve, ve_part, use_part);
  k_gx<<<T_DIM, 256, 0, stream>>>(use_part ? ve_part : ve, use_part ? NCHUNK : 1,
                                  Wih, bih, gx);
  k_gru_att<<<1, 768, 0, stream>>>(Whh, bhh, gx, watt, hs, out);
}